// Round 6
// baseline (255.947 us; speedup 1.0000x reference)
//
#include <hip/hip_runtime.h>
#include <stdint.h>
#include <math.h>

typedef unsigned short u16;
typedef unsigned int   u32;
typedef __attribute__((ext_vector_type(8))) short short8;   // 8 bf16 (4 VGPRs)
typedef __attribute__((ext_vector_type(4))) float f32x4;

#define TT 2048
#define CC 1024

// fp32 -> bf16 RNE (matches HW conversion)
__device__ __forceinline__ u16 f2bf(float f) {
  u32 u = __float_as_uint(f);
  u += 0x7fff + ((u >> 16) & 1);
  return (u16)(u >> 16);
}

__device__ __forceinline__ void gload_lds16(const void* g, void* l) {
  __builtin_amdgcn_global_load_lds((const __attribute__((address_space(1))) void*)g,
                                   (__attribute__((address_space(3))) void*)l, 16, 0, 0);
}

__device__ __forceinline__ u32 cvt_pk_bf16(float lo, float hi) {
  u32 r;
  asm("v_cvt_pk_bf16_f32 %0, %1, %2" : "=v"(r) : "v"(lo), "v"(hi));
  return r;
}

// single-instruction 2^x
__device__ __forceinline__ float expv(float x) {
  float r;
  asm("v_exp_f32 %0, %1" : "=v"(r) : "v"(x));
  return r;
}

// ---------------- fp32 -> bf16 convert: x + all 4 weights in one launch --------
// chunks (float4): [0, 2097152) = x ; then 4 x 262144 for Wq,Wk,Wv,Wp
__global__ __launch_bounds__(256) void cvtAll(const float* __restrict__ x,
                                              const float* __restrict__ w0,
                                              const float* __restrict__ w1,
                                              const float* __restrict__ w2,
                                              const float* __restrict__ w3,
                                              u16* __restrict__ xb,
                                              u16* __restrict__ wb) {
  int i = blockIdx.x * 256 + threadIdx.x;
  const float* src;
  u16* dst;
  if (i < 2097152) {
    src = x; dst = xb;
  } else {
    int g = (i - 2097152) >> 18;           // 0..3
    i = (i - 2097152) & 262143;
    src = (g == 0) ? w0 : (g == 1) ? w1 : (g == 2) ? w2 : w3;
    dst = wb + (size_t)g * 1048576;
  }
  float4 v = ((const float4*)src)[i];
  uint2 o;
  o.x = (u32)f2bf(v.x) | ((u32)f2bf(v.y) << 16);
  o.y = (u32)f2bf(v.z) | ((u32)f2bf(v.w) << 16);
  ((uint2*)dst)[i] = o;
}

// ---------------- fused Q|K GEMM: 256x256 tile, BK=32, ring-4 LDS ----------------
__global__ __launch_bounds__(512, 2) void qk256(const u16* __restrict__ A,
                                                const u16* __restrict__ Bm,
                                                const float* __restrict__ bq,
                                                const float* __restrict__ bk,
                                                u16* __restrict__ Qo,
                                                u16* __restrict__ Ko,
                                                float qscale) {
  constexpr int NBJ = 8;   // 2048/256
  __shared__ __align__(16) u16 lds[4][2][8192];
  const int tid = threadIdx.x;
  const int w = tid >> 6, l = tid & 63, lr = l & 15, lg = l >> 4;
  const int wm = w >> 2, wn = w & 3;
  const int nwg = gridDim.x;
  const int bid = (blockIdx.x & 7) * (nwg >> 3) + (blockIdx.x >> 3);
  const int i0 = (bid / NBJ) << 8, j0 = (bid % NBJ) << 8;

  const u16 *as0, *as1, *bs0, *bs1;
  int cd0, cd1;
  {
    int c0 = tid, c1 = tid + 512;
    int r0 = c0 >> 2, s0 = (c0 & 3) ^ ((r0 >> 1) & 3);
    int r1 = c1 >> 2, s1 = (c1 & 3) ^ ((r1 >> 1) & 3);
    as0 = A + (size_t)(i0 + r0) * 1024 + s0 * 8;
    as1 = A + (size_t)(i0 + r1) * 1024 + s1 * 8;
    bs0 = Bm + (size_t)(j0 + r0) * 1024 + s0 * 8;
    bs1 = Bm + (size_t)(j0 + r1) * 1024 + s1 * 8;
    cd0 = c0 * 8; cd1 = c1 * 8;
  }
  auto issue = [&](int t) {
    const int ko = t * 32;
    u16* la = &lds[t & 3][0][0];
    u16* lb = &lds[t & 3][1][0];
    gload_lds16(as0 + ko, la + cd0);
    gload_lds16(as1 + ko, la + cd1);
    gload_lds16(bs0 + ko, lb + cd0);
    gload_lds16(bs1 + ko, lb + cd1);
  };

  const int slot = lg ^ ((lr >> 1) & 3);
  const int sa = (((wm * 128 + lr) * 64 + slot * 16) >> 1);
  const int sb = (((wn * 64 + lr) * 64 + slot * 16) >> 1);

  f32x4 acc[8][4];
#pragma unroll
  for (int a = 0; a < 8; a++)
#pragma unroll
    for (int b = 0; b < 4; b++) acc[a][b] = f32x4{0.f, 0.f, 0.f, 0.f};

  issue(0); issue(1); issue(2);

  for (int t = 0; t < 32; ++t) {
    if (t + 3 < 32) issue(t + 3);
    if (t < 29)       asm volatile("s_waitcnt vmcnt(12)" ::: "memory");
    else if (t == 29) asm volatile("s_waitcnt vmcnt(8)" ::: "memory");
    else if (t == 30) asm volatile("s_waitcnt vmcnt(4)" ::: "memory");
    else              asm volatile("s_waitcnt vmcnt(0)" ::: "memory");
    __builtin_amdgcn_s_barrier();
    __builtin_amdgcn_sched_barrier(0);
    const u16* la = &lds[t & 3][0][0];
    const u16* lb = &lds[t & 3][1][0];
    short8 bfr[4], af[8];
#pragma unroll
    for (int ff = 0; ff < 4; ++ff) bfr[ff] = *(const short8*)&lb[sb + ff * 512];
#pragma unroll
    for (int f = 0; f < 8; ++f) af[f] = *(const short8*)&la[sa + f * 512];
    asm volatile("s_waitcnt lgkmcnt(0)" ::: "memory");
    __builtin_amdgcn_s_barrier();
    __builtin_amdgcn_sched_barrier(0);
    __builtin_amdgcn_s_setprio(1);
#pragma unroll
    for (int f = 0; f < 8; ++f)
#pragma unroll
      for (int ff = 0; ff < 4; ++ff)
        acc[f][ff] = __builtin_amdgcn_mfma_f32_16x16x32_bf16(af[f], bfr[ff], acc[f][ff], 0, 0, 0);
    __builtin_amdgcn_s_setprio(0);
  }

  const int mat = j0 >> 10;
  const float* bias = mat ? bk : bq;
  u16* outp = mat ? Ko : Qo;
  const float sc = mat ? 1.0f : qscale;
  const int jjb = j0 & 1023;
#pragma unroll
  for (int f = 0; f < 8; ++f)
#pragma unroll
    for (int ff = 0; ff < 4; ++ff) {
      int jq = jjb + wn * 64 + ff * 16 + lr;
      float bv = bias[jq];
      int h = jq >> 6, d = jq & 63;
#pragma unroll
      for (int j2 = 0; j2 < 4; ++j2) {
        int i = i0 + wm * 128 + f * 16 + lg * 4 + j2;
        float v = (acc[f][ff][j2] + bv) * sc;
        outp[(size_t)((i >> 11) * 16 + h) * 131072 + (i & 2047) * 64 + d] = f2bf(v);
      }
    }
}

// ---------------- GEMM (128x128): V^T and proj, 2-barrier counted-vmcnt --------
// MODE 1: bf16 out at [i][j] flat (VT layout), bias[i]
// MODE 2: fp32 out at [i][j], bias[j]
template <int MODE>
__global__ __launch_bounds__(256) void gemm_bt(const u16* __restrict__ A,
                                               const u16* __restrict__ Bm,
                                               const float* __restrict__ bias,
                                               void* __restrict__ outp,
                                               int M, int N, float scale) {
  constexpr int K = 1024;
  __shared__ __align__(16) u16 ldsA[2][128 * 32];
  __shared__ __align__(16) u16 ldsB[2][128 * 32];
  const int tid = threadIdx.x;
  const int w = tid >> 6, l = tid & 63;
  const int lr = l & 15, lg = l >> 4;
  const int nbj = N >> 7;
  const int nwg = gridDim.x;
  const int bid = (blockIdx.x & 7) * (nwg >> 3) + (blockIdx.x >> 3);
  const int i0 = (bid / nbj) << 7;
  const int j0 = (bid % nbj) << 7;
  const int wr = w >> 1, wc = w & 1;

  f32x4 acc[4][4];
#pragma unroll
  for (int a = 0; a < 4; a++)
#pragma unroll
    for (int b = 0; b < 4; b++) acc[a][b] = f32x4{0.f, 0.f, 0.f, 0.f};

  auto stage = [&](int buf, int kt) {
    const u16* sA = A + (size_t)i0 * K + kt * 32;
    const u16* sB = Bm + (size_t)j0 * K + kt * 32;
#pragma unroll
    for (int i = 0; i < 2; ++i) {
      int chunk = w * 128 + i * 64 + l;
      int r = chunk >> 2;
      int co = (chunk & 3) * 8;
      gload_lds16(sA + (size_t)r * K + co, &ldsA[buf][chunk * 8]);
      gload_lds16(sB + (size_t)r * K + co, &ldsB[buf][chunk * 8]);
    }
  };

  stage(0, 0);
  int cur = 0;
  for (int kt = 0; kt < 32; ++kt) {
    if (kt + 1 < 32) {
      stage(cur ^ 1, kt + 1);
      asm volatile("s_waitcnt vmcnt(4)" ::: "memory");
    } else {
      asm volatile("s_waitcnt vmcnt(0)" ::: "memory");
    }
    __builtin_amdgcn_s_barrier();            // #1: buf[cur] ready
    __builtin_amdgcn_sched_barrier(0);
    short8 af[4], bfr[4];
#pragma unroll
    for (int f = 0; f < 4; ++f) {
      af[f]  = *(const short8*)&ldsA[cur][(wr * 64 + f * 16 + lr) * 32 + lg * 8];
      bfr[f] = *(const short8*)&ldsB[cur][(wc * 64 + f * 16 + lr) * 32 + lg * 8];
    }
    asm volatile("s_waitcnt lgkmcnt(0)" ::: "memory");
    __builtin_amdgcn_s_barrier();            // #2: buf[cur] released
    __builtin_amdgcn_sched_barrier(0);
    __builtin_amdgcn_s_setprio(1);
#pragma unroll
    for (int fi = 0; fi < 4; ++fi)
#pragma unroll
      for (int fj = 0; fj < 4; ++fj)
        acc[fi][fj] = __builtin_amdgcn_mfma_f32_16x16x32_bf16(af[fi], bfr[fj], acc[fi][fj], 0, 0, 0);
    __builtin_amdgcn_s_setprio(0);
    cur ^= 1;
  }

#pragma unroll
  for (int fi = 0; fi < 4; ++fi) {
#pragma unroll
    for (int fj = 0; fj < 4; ++fj) {
#pragma unroll
      for (int j2 = 0; j2 < 4; ++j2) {
        int i = i0 + wr * 64 + fi * 16 + lg * 4 + j2;
        int j = j0 + wc * 64 + fj * 16 + lr;
        float v = (acc[fi][fj][j2] + (MODE == 1 ? bias[i] : bias[j])) * scale;
        if constexpr (MODE == 1) {
          ((u16*)outp)[(size_t)i * 8192 + j] = f2bf(v);
        } else {
          ((float*)outp)[(size_t)i * 1024 + j] = v;
        }
      }
    }
  }
}

// ---------------- causal flash attention v4: QK pipelined one tile ahead -------
// Iter u: [issue SV(u+1), SK(u+2)] -> vmcnt -> barrier -> QK(u+1) MFMA ->
// softmax(u) VALU (overlaps QK drain) -> PV(u) MFMA -> barrier.
// K ring-2 is safe: K tile u is dead after QK(u) (computed in iter u-1, barrier
// #2 separates); V ring-2 as before. LDS stays 40KB -> 4 blocks/CU.
__global__ __launch_bounds__(256, 4) void attn_fwd(const u16* __restrict__ Q,
                                                   const u16* __restrict__ Kt,
                                                   const u16* __restrict__ VT,
                                                   u16* __restrict__ Y) {
  const int bid = blockIdx.x;
  const int bh = bid & 63;
  const int p  = bid >> 6;          // pair id 0..15: tiles p and 31-p
  const int b = bh >> 4, h = bh & 15;
  const int w = threadIdx.x >> 6, l = threadIdx.x & 63;
  const int lr = l & 15, lg = l >> 4;

  const u16* Qh = Q + (size_t)bh * (TT * 64);
  const u16* Kh = Kt + (size_t)bh * (TT * 64);
  const u16* Vh = VT + (size_t)(h * 64) * (4 * TT) + (size_t)b * TT;

  __shared__ __align__(16) u16 ldsK[2][32 * 128];  // ring-2, pair-row swizzled
  __shared__ __align__(16) u16 ldsV[2][32 * 128];
  __shared__ __align__(16) u16 plds[4][16 * 64];   // per-wave P, xor-swz
  u16* pw = &plds[w][0];

  const int nA = p + 1;
  const int tileB = 31 - p;

  // hoisted staging addresses
  const u16 *ks0, *ks1, *vs0, *vs1;
  int cd0, cd1;
  {
    int c0 = threadIdx.x, c1 = threadIdx.x + 256;
    int r0 = c0 >> 4, sw0 = (c0 & 15) ^ (r0 & 15);
    int r1 = c1 >> 4, sw1 = (c1 & 15) ^ (r1 & 15);
    int kl0 = 2 * r0 + (sw0 >> 3), co0 = (sw0 & 7) * 8;
    int kl1 = 2 * r1 + (sw1 >> 3), co1 = (sw1 & 7) * 8;
    ks0 = Kh + (size_t)kl0 * 64 + co0;
    ks1 = Kh + (size_t)kl1 * 64 + co1;
    vs0 = Vh + (size_t)kl0 * (4 * TT) + co0;
    vs1 = Vh + (size_t)kl1 * (4 * TT) + co1;
    cd0 = c0 * 8; cd1 = c1 * 8;
  }
  auto stageK = [&](int buf, int kc0) {
    gload_lds16(ks0 + (size_t)kc0 * 64, &ldsK[buf][cd0]);
    gload_lds16(ks1 + (size_t)kc0 * 64, &ldsK[buf][cd1]);
  };
  auto stageV = [&](int buf, int kc0) {
    gload_lds16(vs0 + kc0, &ldsV[buf][cd0]);
    gload_lds16(vs1 + kc0, &ldsV[buf][cd1]);
  };
  auto ktof = [&](int u) { return u < nA ? u : u - nA; };

  // hoisted LDS read offsets (u16 idx)
  int kof[4][2], vof[4][2];
#pragma unroll
  for (int fk = 0; fk < 4; ++fk)
#pragma unroll
    for (int fd = 0; fd < 2; ++fd) {
      int kl = fk * 16 + lr;
      int r2 = kl >> 1;
      int b2 = (((kl & 1) << 7) | (fd * 64 + lg * 16)) ^ ((r2 & 15) << 4);
      kof[fk][fd] = r2 * 128 + (b2 >> 1);
    }
#pragma unroll
  for (int fd = 0; fd < 4; ++fd)
#pragma unroll
    for (int ks = 0; ks < 2; ++ks) {
      int dl = fd * 16 + lr;
      int r2 = dl >> 1;
      int b2 = (((dl & 1) << 7) | (ks * 64 + lg * 16)) ^ ((r2 & 15) << 4);
      vof[fd][ks] = r2 * 128 + (b2 >> 1);
    }
  int pwo[4], pro[2];
#pragma unroll
  for (int fk = 0; fk < 4; ++fk)
    pwo[fk] = lr * 64 + ((fk * 16 + lg * 4) ^ ((lr & 7) << 3));
#pragma unroll
  for (int ks = 0; ks < 2; ++ks)
    pro[ks] = lr * 64 + ((ks * 32 + lg * 8) ^ ((lr & 7) << 3));

  short8 onesf;
#pragma unroll
  for (int i = 0; i < 8; ++i) onesf[i] = (short)0x3F80;  // bf16 1.0

  // both tiles' Q fragments preloaded (QK(u+1) at the tile boundary needs qfB
  // while tile A's accumulators are still live)
  short8 qfA[2], qfB[2];
  {
    int qa = p * 64 + w * 16, qb = tileB * 64 + w * 16;
#pragma unroll
    for (int fd = 0; fd < 2; ++fd) {
      qfA[fd] = *(const short8*)&Qh[(size_t)(qa + lr) * 64 + fd * 32 + lg * 8];
      qfB[fd] = *(const short8*)&Qh[(size_t)(qb + lr) * 64 + fd * 32 + lg * 8];
    }
  }

  f32x4 ot[4];
  f32x4 lsacc;
  int q0 = p * 64 + w * 16;
#pragma unroll
  for (int fd = 0; fd < 4; ++fd) ot[fd] = f32x4{0.f, 0.f, 0.f, 0.f};
  lsacc = f32x4{0.f, 0.f, 0.f, 0.f};

  auto epilogue = [&]() {
    float inv = 1.0f / lsacc[0];
    const int q = q0 + lr;
#pragma unroll
    for (int fd = 0; fd < 4; ++fd) {
      uint2 o;
      o.x = cvt_pk_bf16(ot[fd][0] * inv, ot[fd][1] * inv);
      o.y = cvt_pk_bf16(ot[fd][2] * inv, ot[fd][3] * inv);
      *(uint2*)&Y[(size_t)(b * TT + q) * CC + h * 64 + fd * 16 + lg * 4] = o;
    }
  };

  f32x4 stA[4], stB[4];

  // QK compute: S^T(tile) += K.Q^T, first-fd uses zero C (no explicit init)
  auto qk = [&](f32x4 (&st)[4], const u16* lk, const short8 (&qf)[2]) {
    __builtin_amdgcn_s_setprio(1);
#pragma unroll
    for (int fk = 0; fk < 4; ++fk)
      st[fk] = __builtin_amdgcn_mfma_f32_16x16x32_bf16(*(const short8*)&lk[kof[fk][0]],
                                                       qf[0], f32x4{0.f, 0.f, 0.f, 0.f}, 0, 0, 0);
#pragma unroll
    for (int fk = 0; fk < 4; ++fk)
      st[fk] = __builtin_amdgcn_mfma_f32_16x16x32_bf16(*(const short8*)&lk[kof[fk][1]],
                                                       qf[1], st[fk], 0, 0, 0);
    __builtin_amdgcn_s_setprio(0);
  };

  // prologue: SV(0), SK(0), SK(1) -> wait SV0,SK0 -> barrier -> QK(0)
  stageV(0, 0);
  stageK(0, 0);
  stageK(1, ktof(1) << 6);
  asm volatile("s_waitcnt vmcnt(2)" ::: "memory");
  __builtin_amdgcn_s_barrier();
  __builtin_amdgcn_sched_barrier(0);
  qk(stA, &ldsK[0][0], qfA);

  for (int u = 0; u < 33; ++u) {
    const int kc0 = ktof(u) << 6;
    // issue next staging (buffers freed by barrier #2 of iter u-1 / analysis above)
    if (u + 1 < 33) stageV((u + 1) & 1, ktof(u + 1) << 6);
    if (u + 2 < 33) stageK(u & 1, ktof(u + 2) << 6);
    // counted wait: complete SV(u), SK(u+1); leave this iter's issues in flight
    if (u < 31)       asm volatile("s_waitcnt vmcnt(4)" ::: "memory");
    else if (u == 31) asm volatile("s_waitcnt vmcnt(2)" ::: "memory");
    else              asm volatile("s_waitcnt vmcnt(0)" ::: "memory");
    __builtin_amdgcn_s_barrier();            // #1: K(u+1), V(u) ready
    __builtin_amdgcn_sched_barrier(0);
    // ---- QK(u+1) MFMA (issues first; softmax VALU below overlaps its drain) ----
    if (u + 1 < 33) {
      const u16* lk = &ldsK[(u + 1) & 1][0];
      if (u + 1 < nA) qk(stB, lk, qfA);
      else            qk(stB, lk, qfB);
    }
    // ---- softmax(u) on stA ----
    if ((u == nA - 1) || (u == 32)) {
      const int q = q0 + lr;
#pragma unroll
      for (int fk = 0; fk < 4; ++fk)
#pragma unroll
        for (int j = 0; j < 4; ++j) {
          int k = kc0 + fk * 16 + lg * 4 + j;
          if (k > q) stA[fk][j] = -1e30f;
        }
    }
#pragma unroll
    for (int fk = 0; fk < 4; ++fk) {
      uint2 pk2;
      pk2.x = cvt_pk_bf16(expv(stA[fk][0]), expv(stA[fk][1]));
      pk2.y = cvt_pk_bf16(expv(stA[fk][2]), expv(stA[fk][3]));
      *(uint2*)&pw[pwo[fk]] = pk2;
    }
    asm volatile("s_waitcnt lgkmcnt(0)" ::: "memory");
    __builtin_amdgcn_sched_barrier(0);
    // ---- PV(u): O^T += V^T.P^T ; lsum += 1.P^T ----
    {
      const u16* lv = &ldsV[u & 1][0];
      __builtin_amdgcn_s_setprio(1);
#pragma unroll
      for (int ks = 0; ks < 2; ++ks) {
        short8 pf = *(const short8*)&pw[pro[ks]];
        lsacc = __builtin_amdgcn_mfma_f32_16x16x32_bf16(onesf, pf, lsacc, 0, 0, 0);
#pragma unroll
        for (int fd = 0; fd < 4; ++fd)
          ot[fd] = __builtin_amdgcn_mfma_f32_16x16x32_bf16(*(const short8*)&lv[vof[fd][ks]],
                                                           pf, ot[fd], 0, 0, 0);
      }
      __builtin_amdgcn_s_setprio(0);
    }
    __builtin_amdgcn_s_barrier();            // #2: V(u) / K(u+1) consumers done
    __builtin_amdgcn_sched_barrier(0);
    // advance pipeline state
#pragma unroll
    for (int fk = 0; fk < 4; ++fk) stA[fk] = stB[fk];
    if (u == nA - 1) {                       // tile A finished
      epilogue();
      q0 = tileB * 64 + w * 16;
#pragma unroll
      for (int fd = 0; fd < 4; ++fd) ot[fd] = f32x4{0.f, 0.f, 0.f, 0.f};
      lsacc = f32x4{0.f, 0.f, 0.f, 0.f};
    }
  }
  epilogue();
}

extern "C" void kernel_launch(void* const* d_in, const int* in_sizes, int n_in,
                              void* d_out, int out_size, void* d_ws, size_t ws_size,
                              hipStream_t stream) {
  const float* x  = (const float*)d_in[0];
  const float* Wq = (const float*)d_in[1];
  const float* bq = (const float*)d_in[2];
  const float* Wk = (const float*)d_in[3];
  const float* bk = (const float*)d_in[4];
  const float* Wv = (const float*)d_in[5];
  const float* bv = (const float*)d_in[6];
  const float* Wp = (const float*)d_in[7];
  const float* bp = (const float*)d_in[8];
  float* out = (float*)d_out;

  u16* ws  = (u16*)d_ws;
  u16* xb  = ws;                  // 8388608 (x bf16; later reused as Y)
  u16* wqb = xb + 8388608;        // Wq,Wk,Wv,Wp contiguous (1048576 each)
  u16* wkb = wqb + 1048576;
  u16* wvb = wkb + 1048576;
  u16* wpb = wvb + 1048576;
  u16* Qb  = wpb + 1048576;
  u16* Kb  = Qb + 8388608;
  u16* VTb = Kb + 8388608;
  u16* Yb  = xb;
  (void)wkb;

  cvtAll<<<12288, 256, 0, stream>>>(x, Wq, Wk, Wv, Wp, xb, wqb);

  // fused Q|K projection; Q pre-scaled by (1/sqrt(D)) * log2(e)
  qk256<<<256, 512, 0, stream>>>(xb, wqb, bq, bk, Qb, Kb,
                                 0.125f * 1.44269504088896340736f);
  // V^T = Wv . x^T  -> VT[n = h*64+d][m = b*T+t]
  gemm_bt<1><<<512, 256, 0, stream>>>(wvb, xb, bv, VTb, 1024, 8192, 1.0f);

  attn_fwd<<<1024, 256, 0, stream>>>(Qb, Kb, VTb, Yb);

  gemm_bt<2><<<512, 256, 0, stream>>>(Yb, wpb, bp, out, 8192, 1024, 1.0f);
}

// Round 7
// 248.884 us; speedup vs baseline: 1.0284x; 1.0284x over previous
//
#include <hip/hip_runtime.h>
#include <stdint.h>
#include <math.h>

typedef unsigned short u16;
typedef unsigned int   u32;
typedef __attribute__((ext_vector_type(8))) short short8;   // 8 bf16 (4 VGPRs)
typedef __attribute__((ext_vector_type(4))) float f32x4;

#define TT 2048
#define CC 1024

// fp32 -> bf16 RNE (matches HW conversion)
__device__ __forceinline__ u16 f2bf(float f) {
  u32 u = __float_as_uint(f);
  u += 0x7fff + ((u >> 16) & 1);
  return (u16)(u >> 16);
}

__device__ __forceinline__ void gload_lds16(const void* g, void* l) {
  __builtin_amdgcn_global_load_lds((const __attribute__((address_space(1))) void*)g,
                                   (__attribute__((address_space(3))) void*)l, 16, 0, 0);
}

__device__ __forceinline__ u32 cvt_pk_bf16(float lo, float hi) {
  u32 r;
  asm("v_cvt_pk_bf16_f32 %0, %1, %2" : "=v"(r) : "v"(lo), "v"(hi));
  return r;
}

// single-instruction 2^x
__device__ __forceinline__ float expv(float x) {
  float r;
  asm("v_exp_f32 %0, %1" : "=v"(r) : "v"(x));
  return r;
}

// ---------------- fp32 -> bf16 convert: x + all 4 weights in one launch --------
__global__ __launch_bounds__(256) void cvtAll(const float* __restrict__ x,
                                              const float* __restrict__ w0,
                                              const float* __restrict__ w1,
                                              const float* __restrict__ w2,
                                              const float* __restrict__ w3,
                                              u16* __restrict__ xb,
                                              u16* __restrict__ wb) {
  int i = blockIdx.x * 256 + threadIdx.x;
  const float* src;
  u16* dst;
  if (i < 2097152) {
    src = x; dst = xb;
  } else {
    int g = (i - 2097152) >> 18;           // 0..3
    i = (i - 2097152) & 262143;
    src = (g == 0) ? w0 : (g == 1) ? w1 : (g == 2) ? w2 : w3;
    dst = wb + (size_t)g * 1048576;
  }
  float4 v = ((const float4*)src)[i];
  uint2 o;
  o.x = (u32)f2bf(v.x) | ((u32)f2bf(v.y) << 16);
  o.y = (u32)f2bf(v.z) | ((u32)f2bf(v.w) << 16);
  ((uint2*)dst)[i] = o;
}

// ---------------- fused Q|K|V GEMM: 256x256 tile, BK=32, ring-4 LDS ------------
// C[i][j] = sum_k A[i][k]*Bm[j][k] + bias[j], Bm = Wq||Wk||Wv (3072 rows).
// j<1024 -> Q [B,H,T,D] (scaled); j<2048 -> K [B,H,T,D]; else V -> VT[j'][i].
__global__ __launch_bounds__(512, 2) void qkv256(const u16* __restrict__ A,
                                                 const u16* __restrict__ Bm,
                                                 const float* __restrict__ bq,
                                                 const float* __restrict__ bk,
                                                 const float* __restrict__ bv,
                                                 u16* __restrict__ Qo,
                                                 u16* __restrict__ Ko,
                                                 u16* __restrict__ VTo,
                                                 float qscale) {
  constexpr int NBJ = 12;   // 3072/256
  __shared__ __align__(16) u16 lds[4][2][8192];
  const int tid = threadIdx.x;
  const int w = tid >> 6, l = tid & 63, lr = l & 15, lg = l >> 4;
  const int wm = w >> 2, wn = w & 3;
  const int nwg = gridDim.x;
  const int bid = (blockIdx.x & 7) * (nwg >> 3) + (blockIdx.x >> 3);
  const int i0 = (bid / NBJ) << 8, j0 = (bid % NBJ) << 8;

  const u16 *as0, *as1, *bs0, *bs1;
  int cd0, cd1;
  {
    int c0 = tid, c1 = tid + 512;
    int r0 = c0 >> 2, s0 = (c0 & 3) ^ ((r0 >> 1) & 3);
    int r1 = c1 >> 2, s1 = (c1 & 3) ^ ((r1 >> 1) & 3);
    as0 = A + (size_t)(i0 + r0) * 1024 + s0 * 8;
    as1 = A + (size_t)(i0 + r1) * 1024 + s1 * 8;
    bs0 = Bm + (size_t)(j0 + r0) * 1024 + s0 * 8;
    bs1 = Bm + (size_t)(j0 + r1) * 1024 + s1 * 8;
    cd0 = c0 * 8; cd1 = c1 * 8;
  }
  auto issue = [&](int t) {
    const int ko = t * 32;
    u16* la = &lds[t & 3][0][0];
    u16* lb = &lds[t & 3][1][0];
    gload_lds16(as0 + ko, la + cd0);
    gload_lds16(as1 + ko, la + cd1);
    gload_lds16(bs0 + ko, lb + cd0);
    gload_lds16(bs1 + ko, lb + cd1);
  };

  const int slot = lg ^ ((lr >> 1) & 3);
  const int sa = (((wm * 128 + lr) * 64 + slot * 16) >> 1);
  const int sb = (((wn * 64 + lr) * 64 + slot * 16) >> 1);

  f32x4 acc[8][4];
#pragma unroll
  for (int a = 0; a < 8; a++)
#pragma unroll
    for (int b = 0; b < 4; b++) acc[a][b] = f32x4{0.f, 0.f, 0.f, 0.f};

  issue(0); issue(1); issue(2);

  for (int t = 0; t < 32; ++t) {
    if (t + 3 < 32) issue(t + 3);
    if (t < 29)       asm volatile("s_waitcnt vmcnt(12)" ::: "memory");
    else if (t == 29) asm volatile("s_waitcnt vmcnt(8)" ::: "memory");
    else if (t == 30) asm volatile("s_waitcnt vmcnt(4)" ::: "memory");
    else              asm volatile("s_waitcnt vmcnt(0)" ::: "memory");
    __builtin_amdgcn_s_barrier();
    __builtin_amdgcn_sched_barrier(0);
    const u16* la = &lds[t & 3][0][0];
    const u16* lb = &lds[t & 3][1][0];
    short8 bfr[4], af[8];
#pragma unroll
    for (int ff = 0; ff < 4; ++ff) bfr[ff] = *(const short8*)&lb[sb + ff * 512];
#pragma unroll
    for (int f = 0; f < 8; ++f) af[f] = *(const short8*)&la[sa + f * 512];
    asm volatile("s_waitcnt lgkmcnt(0)" ::: "memory");
    __builtin_amdgcn_s_barrier();
    __builtin_amdgcn_sched_barrier(0);
    __builtin_amdgcn_s_setprio(1);
#pragma unroll
    for (int f = 0; f < 8; ++f)
#pragma unroll
      for (int ff = 0; ff < 4; ++ff)
        acc[f][ff] = __builtin_amdgcn_mfma_f32_16x16x32_bf16(af[f], bfr[ff], acc[f][ff], 0, 0, 0);
    __builtin_amdgcn_s_setprio(0);
  }

  const int mat = j0 >> 10;                // 0=Q, 1=K, 2=V
  const int jjb = j0 & 1023;
  if (mat == 2) {
    // V: write VT[j'][i] (stride 8192), 4 consecutive tokens per lane -> uint2
#pragma unroll
    for (int f = 0; f < 8; ++f)
#pragma unroll
      for (int ff = 0; ff < 4; ++ff) {
        int jq = jjb + wn * 64 + ff * 16 + lr;
        float bb = bv[jq];
        int ib = i0 + wm * 128 + f * 16 + lg * 4;
        uint2 o;
        o.x = cvt_pk_bf16(acc[f][ff][0] + bb, acc[f][ff][1] + bb);
        o.y = cvt_pk_bf16(acc[f][ff][2] + bb, acc[f][ff][3] + bb);
        *(uint2*)&VTo[(size_t)jq * 8192 + ib] = o;
      }
  } else {
    const float* bias = mat ? bk : bq;
    u16* outp = mat ? Ko : Qo;
    const float sc = mat ? 1.0f : qscale;
#pragma unroll
    for (int f = 0; f < 8; ++f)
#pragma unroll
      for (int ff = 0; ff < 4; ++ff) {
        int jq = jjb + wn * 64 + ff * 16 + lr;
        float bb = bias[jq];
        int h = jq >> 6, d = jq & 63;
#pragma unroll
        for (int j2 = 0; j2 < 4; ++j2) {
          int i = i0 + wm * 128 + f * 16 + lg * 4 + j2;
          float v = (acc[f][ff][j2] + bb) * sc;
          outp[(size_t)((i >> 11) * 16 + h) * 131072 + (i & 2047) * 64 + d] = f2bf(v);
        }
      }
  }
}

// ---------------- proj GEMM (128x128): ring-4, counted vmcnt(12) ---------------
// fp32 out at [i][j] (i*1024+j), bias[j]
__global__ __launch_bounds__(256) void gemm_proj(const u16* __restrict__ A,
                                                 const u16* __restrict__ Bm,
                                                 const float* __restrict__ bias,
                                                 float* __restrict__ outp,
                                                 int N) {
  constexpr int K = 1024;
  __shared__ __align__(16) u16 ldsA[4][128 * 32];
  __shared__ __align__(16) u16 ldsB[4][128 * 32];
  const int tid = threadIdx.x;
  const int w = tid >> 6, l = tid & 63;
  const int lr = l & 15, lg = l >> 4;
  const int nbj = N >> 7;
  const int nwg = gridDim.x;
  const int bid = (blockIdx.x & 7) * (nwg >> 3) + (blockIdx.x >> 3);
  const int i0 = (bid / nbj) << 7;
  const int j0 = (bid % nbj) << 7;
  const int wr = w >> 1, wc = w & 1;

  f32x4 acc[4][4];
#pragma unroll
  for (int a = 0; a < 4; a++)
#pragma unroll
    for (int b = 0; b < 4; b++) acc[a][b] = f32x4{0.f, 0.f, 0.f, 0.f};

  const u16 *sa0, *sa1, *sb0, *sb1;
  int cd0, cd1;
  {
    int c0 = tid, c1 = tid + 256;
    int r0 = c0 >> 2, o0 = (c0 & 3) * 8;
    int r1 = c1 >> 2, o1 = (c1 & 3) * 8;
    sa0 = A + (size_t)(i0 + r0) * K + o0;
    sa1 = A + (size_t)(i0 + r1) * K + o1;
    sb0 = Bm + (size_t)(j0 + r0) * K + o0;
    sb1 = Bm + (size_t)(j0 + r1) * K + o1;
    cd0 = c0 * 8; cd1 = c1 * 8;
  }
  auto issue = [&](int t) {
    const int ko = t * 32;
    gload_lds16(sa0 + ko, &ldsA[t & 3][cd0]);
    gload_lds16(sa1 + ko, &ldsA[t & 3][cd1]);
    gload_lds16(sb0 + ko, &ldsB[t & 3][cd0]);
    gload_lds16(sb1 + ko, &ldsB[t & 3][cd1]);
  };

  issue(0); issue(1); issue(2);

  for (int t = 0; t < 32; ++t) {
    if (t + 3 < 32) issue(t + 3);
    if (t < 29)       asm volatile("s_waitcnt vmcnt(12)" ::: "memory");
    else if (t == 29) asm volatile("s_waitcnt vmcnt(8)" ::: "memory");
    else if (t == 30) asm volatile("s_waitcnt vmcnt(4)" ::: "memory");
    else              asm volatile("s_waitcnt vmcnt(0)" ::: "memory");
    __builtin_amdgcn_s_barrier();            // #1: buf[t&3] ready
    __builtin_amdgcn_sched_barrier(0);
    short8 af[4], bfr[4];
#pragma unroll
    for (int f = 0; f < 4; ++f) {
      af[f]  = *(const short8*)&ldsA[t & 3][(wr * 64 + f * 16 + lr) * 32 + lg * 8];
      bfr[f] = *(const short8*)&ldsB[t & 3][(wc * 64 + f * 16 + lr) * 32 + lg * 8];
    }
    asm volatile("s_waitcnt lgkmcnt(0)" ::: "memory");
    __builtin_amdgcn_s_barrier();            // #2: buf[t&3] released
    __builtin_amdgcn_sched_barrier(0);
    __builtin_amdgcn_s_setprio(1);
#pragma unroll
    for (int fi = 0; fi < 4; ++fi)
#pragma unroll
      for (int fj = 0; fj < 4; ++fj)
        acc[fi][fj] = __builtin_amdgcn_mfma_f32_16x16x32_bf16(af[fi], bfr[fj], acc[fi][fj], 0, 0, 0);
    __builtin_amdgcn_s_setprio(0);
  }

#pragma unroll
  for (int fi = 0; fi < 4; ++fi) {
#pragma unroll
    for (int fj = 0; fj < 4; ++fj) {
#pragma unroll
      for (int j2 = 0; j2 < 4; ++j2) {
        int i = i0 + wr * 64 + fi * 16 + lg * 4 + j2;
        int j = j0 + wc * 64 + fj * 16 + lr;
        outp[(size_t)i * 1024 + j] = acc[fi][fj][j2] + bias[j];
      }
    }
  }
}

// ---------------- causal flash attention (R5 v3: balanced pairs, counted-vmcnt) -
__global__ __launch_bounds__(256, 4) void attn_fwd(const u16* __restrict__ Q,
                                                   const u16* __restrict__ Kt,
                                                   const u16* __restrict__ VT,
                                                   u16* __restrict__ Y) {
  const int bid = blockIdx.x;
  const int bh = bid & 63;
  const int p  = bid >> 6;          // pair id 0..15: tiles p and 31-p
  const int b = bh >> 4, h = bh & 15;
  const int w = threadIdx.x >> 6, l = threadIdx.x & 63;
  const int lr = l & 15, lg = l >> 4;

  const u16* Qh = Q + (size_t)bh * (TT * 64);
  const u16* Kh = Kt + (size_t)bh * (TT * 64);
  const u16* Vh = VT + (size_t)(h * 64) * (4 * TT) + (size_t)b * TT;

  __shared__ __align__(16) u16 ldsK[2][32 * 128];  // 8KB/buf, pair-row swizzled
  __shared__ __align__(16) u16 ldsV[2][32 * 128];
  __shared__ __align__(16) u16 plds[4][16 * 64];   // per-wave P, xor-swz
  u16* pw = &plds[w][0];

  const int nA = p + 1;
  const int tileB = 31 - p;

  // hoisted staging addresses
  const u16 *ks0, *ks1, *vs0, *vs1;
  int cd0, cd1;
  {
    int c0 = threadIdx.x, c1 = threadIdx.x + 256;
    int r0 = c0 >> 4, sw0 = (c0 & 15) ^ (r0 & 15);
    int r1 = c1 >> 4, sw1 = (c1 & 15) ^ (r1 & 15);
    int kl0 = 2 * r0 + (sw0 >> 3), co0 = (sw0 & 7) * 8;
    int kl1 = 2 * r1 + (sw1 >> 3), co1 = (sw1 & 7) * 8;
    ks0 = Kh + (size_t)kl0 * 64 + co0;
    ks1 = Kh + (size_t)kl1 * 64 + co1;
    vs0 = Vh + (size_t)kl0 * (4 * TT) + co0;
    vs1 = Vh + (size_t)kl1 * (4 * TT) + co1;
    cd0 = c0 * 8; cd1 = c1 * 8;
  }
  auto stageKV = [&](int buf, int kc0) {
    gload_lds16(ks0 + (size_t)kc0 * 64, &ldsK[buf][cd0]);
    gload_lds16(ks1 + (size_t)kc0 * 64, &ldsK[buf][cd1]);
    gload_lds16(vs0 + kc0, &ldsV[buf][cd0]);
    gload_lds16(vs1 + kc0, &ldsV[buf][cd1]);
  };

  // hoisted LDS read offsets (u16 idx)
  int kof[4][2], vof[4][2];
#pragma unroll
  for (int fk = 0; fk < 4; ++fk)
#pragma unroll
    for (int fd = 0; fd < 2; ++fd) {
      int kl = fk * 16 + lr;
      int r2 = kl >> 1;
      int b2 = (((kl & 1) << 7) | (fd * 64 + lg * 16)) ^ ((r2 & 15) << 4);
      kof[fk][fd] = r2 * 128 + (b2 >> 1);
    }
#pragma unroll
  for (int fd = 0; fd < 4; ++fd)
#pragma unroll
    for (int ks = 0; ks < 2; ++ks) {
      int dl = fd * 16 + lr;
      int r2 = dl >> 1;
      int b2 = (((dl & 1) << 7) | (ks * 64 + lg * 16)) ^ ((r2 & 15) << 4);
      vof[fd][ks] = r2 * 128 + (b2 >> 1);
    }
  int pwo[4], pro[2];
#pragma unroll
  for (int fk = 0; fk < 4; ++fk)
    pwo[fk] = lr * 64 + ((fk * 16 + lg * 4) ^ ((lr & 7) << 3));
#pragma unroll
  for (int ks = 0; ks < 2; ++ks)
    pro[ks] = lr * 64 + ((ks * 32 + lg * 8) ^ ((lr & 7) << 3));

  short8 onesf;
#pragma unroll
  for (int i = 0; i < 8; ++i) onesf[i] = (short)0x3F80;  // bf16 1.0

  short8 qf[2];
  f32x4 ot[4];
  f32x4 lsacc;   // lsacc[j] = sum_k P[k][q=lr] (all j equal)
  int q0;
  auto loadQ = [&](int tile) {
    q0 = tile * 64 + w * 16;
#pragma unroll
    for (int fd = 0; fd < 2; ++fd)
      qf[fd] = *(const short8*)&Qh[(size_t)(q0 + lr) * 64 + fd * 32 + lg * 8];
#pragma unroll
    for (int fd = 0; fd < 4; ++fd) ot[fd] = f32x4{0.f, 0.f, 0.f, 0.f};
    lsacc = f32x4{0.f, 0.f, 0.f, 0.f};
  };
  auto epilogue = [&]() {
    float inv = 1.0f / lsacc[0];
    const int q = q0 + lr;
#pragma unroll
    for (int fd = 0; fd < 4; ++fd) {
      uint2 o;
      o.x = cvt_pk_bf16(ot[fd][0] * inv, ot[fd][1] * inv);
      o.y = cvt_pk_bf16(ot[fd][2] * inv, ot[fd][3] * inv);
      *(uint2*)&Y[(size_t)(b * TT + q) * CC + h * 64 + fd * 16 + lg * 4] = o;
    }
  };

  loadQ(p);
  stageKV(0, 0);
  int cur = 0;
  for (int u = 0; u < 33; ++u) {
    const bool inA = u < nA;
    const int kt = inA ? u : u - nA;
    const int kc0 = kt << 6;
    if (u + 1 < 33) {
      int kt2 = (u + 1 < nA) ? u + 1 : u + 1 - nA;
      stageKV(cur ^ 1, kt2 << 6);
      asm volatile("s_waitcnt vmcnt(4)" ::: "memory");
    } else {
      asm volatile("s_waitcnt vmcnt(0)" ::: "memory");
    }
    __builtin_amdgcn_s_barrier();            // #1: buf[cur] ready
    __builtin_amdgcn_sched_barrier(0);
    const u16* lk = &ldsK[cur][0];
    const u16* lv = &ldsV[cur][0];
    // ---- S^T = K · Q^T ----
    f32x4 st[4];
#pragma unroll
    for (int a = 0; a < 4; a++) st[a] = f32x4{0.f, 0.f, 0.f, 0.f};
    __builtin_amdgcn_s_setprio(1);
#pragma unroll
    for (int fd = 0; fd < 2; ++fd)
#pragma unroll
      for (int fk = 0; fk < 4; ++fk)
        st[fk] = __builtin_amdgcn_mfma_f32_16x16x32_bf16(*(const short8*)&lk[kof[fk][fd]],
                                                         qf[fd], st[fk], 0, 0, 0);
    __builtin_amdgcn_s_setprio(0);
    // ---- causal mask on diagonal tiles ----
    if ((u == nA - 1) || (u == 32)) {
      const int q = q0 + lr;
#pragma unroll
      for (int fk = 0; fk < 4; ++fk)
#pragma unroll
        for (int j = 0; j < 4; ++j) {
          int k = kc0 + fk * 16 + lg * 4 + j;
          if (k > q) st[fk][j] = -1e30f;
        }
    }
    // ---- P = exp2(S), packed to bf16 in LDS; sum via ones-MFMA ----
#pragma unroll
    for (int fk = 0; fk < 4; ++fk) {
      uint2 pk2;
      pk2.x = cvt_pk_bf16(expv(st[fk][0]), expv(st[fk][1]));
      pk2.y = cvt_pk_bf16(expv(st[fk][2]), expv(st[fk][3]));
      *(uint2*)&pw[pwo[fk]] = pk2;
    }
    asm volatile("s_waitcnt lgkmcnt(0)" ::: "memory");
    __builtin_amdgcn_sched_barrier(0);
    // ---- O^T += V^T · P^T ;  lsum += 1 · P^T ----
    __builtin_amdgcn_s_setprio(1);
#pragma unroll
    for (int ks = 0; ks < 2; ++ks) {
      short8 pf = *(const short8*)&pw[pro[ks]];
      lsacc = __builtin_amdgcn_mfma_f32_16x16x32_bf16(onesf, pf, lsacc, 0, 0, 0);
#pragma unroll
      for (int fd = 0; fd < 4; ++fd)
        ot[fd] = __builtin_amdgcn_mfma_f32_16x16x32_bf16(*(const short8*)&lv[vof[fd][ks]],
                                                         pf, ot[fd], 0, 0, 0);
    }
    __builtin_amdgcn_s_setprio(0);
    asm volatile("s_waitcnt lgkmcnt(0)" ::: "memory");
    __builtin_amdgcn_s_barrier();            // #2: buf[cur] released
    __builtin_amdgcn_sched_barrier(0);
    cur ^= 1;
    if (u == nA - 1) {
      epilogue();
      loadQ(tileB);
    }
  }
  epilogue();
}

extern "C" void kernel_launch(void* const* d_in, const int* in_sizes, int n_in,
                              void* d_out, int out_size, void* d_ws, size_t ws_size,
                              hipStream_t stream) {
  const float* x  = (const float*)d_in[0];
  const float* Wq = (const float*)d_in[1];
  const float* bq = (const float*)d_in[2];
  const float* Wk = (const float*)d_in[3];
  const float* bk = (const float*)d_in[4];
  const float* Wv = (const float*)d_in[5];
  const float* bv = (const float*)d_in[6];
  const float* Wp = (const float*)d_in[7];
  const float* bp = (const float*)d_in[8];
  float* out = (float*)d_out;

  u16* ws  = (u16*)d_ws;
  u16* xb  = ws;                  // 8388608 (x bf16; later reused as Y)
  u16* wqb = xb + 8388608;        // Wq,Wk,Wv,Wp contiguous (1048576 each)
  u16* wpb = wqb + 3145728;
  u16* Qb  = wpb + 1048576;
  u16* Kb  = Qb + 8388608;
  u16* VTb = Kb + 8388608;
  u16* Yb  = xb;

  cvtAll<<<12288, 256, 0, stream>>>(x, Wq, Wk, Wv, Wp, xb, wqb);

  // fused Q|K|V projection; Q pre-scaled by (1/sqrt(D)) * log2(e)
  qkv256<<<384, 512, 0, stream>>>(xb, wqb, bq, bk, bv, Qb, Kb, VTb,
                                  0.125f * 1.44269504088896340736f);

  attn_fwd<<<1024, 256, 0, stream>>>(Qb, Kb, VTb, Yb);

  gemm_proj<<<512, 256, 0, stream>>>(Yb, wpb, bp, out, 1024);
}